// Round 20
// baseline (128.837 us; speedup 1.0000x reference)
//
#include <hip/hip_runtime.h>
#include <hip/hip_bf16.h>

// Problem constants
#define BATCH   2048
#define HW      81          // 9x9
#define CIN     39
#define NPIX    (BATCH*HW)  // 165888

// ws layout (float offsets)
#define WS_H1     0              // 10,616,832 floats  (B,64,81)  PRE-BN h
#define WS_WDT    12109824       // 36,864 ushort bf16 [k][o][c]   (18,432 floats)
#define WS_W1M    12128256       // 24,576 ushort bf16 [12][64][32] (12,288 floats)
#define WS_WCM    12140544       // 18,432 ushort bf16 [18][32][32] (9,216 floats)
#define WS_STATS  12149760       // 8192 floats: sum1[2048],sq1[2048],sum2[2048],sq2[2048]

#define OUT_OFF_BASE 1
#define OUT_H_BASE   (1 + BATCH*18*81)   // 2985985

typedef __attribute__((ext_vector_type(8))) short bfrag8;
typedef __attribute__((ext_vector_type(4))) float floatx4;

__device__ __forceinline__ unsigned short f2bf(float f) {
    unsigned u = __builtin_bit_cast(unsigned, f);
    u += 0x7FFFu + ((u >> 16) & 1u);       // round-to-nearest-even
    return (unsigned short)(u >> 16);
}
__device__ __forceinline__ float bfhi2f(unsigned hi16) {   // hi16 already in bits 31..16
    return __builtin_bit_cast(float, hi16);
}

// ---------------- weight prep: fragment-ready bf16 layouts --------------------
__global__ void prep_weights(const float* __restrict__ w1, const float* __restrict__ wo,
                             const float* __restrict__ wm, const float* __restrict__ wd,
                             float* __restrict__ ws) {
    int idx = blockIdx.x * 256 + threadIdx.x;
    unsigned short* w1m = (unsigned short*)(ws + WS_W1M);
    unsigned short* wcm = (unsigned short*)(ws + WS_WCM);
    unsigned short* wdt16 = (unsigned short*)(ws + WS_WDT);
    if (idx < 24576) {
        int kk = idx & 31, o = (idx >> 5) & 63, s = idx >> 11;
        int tap, c; bool ok = true;
        if (s < 9)       { tap = s;             c = kk; }
        else if (s == 9) { tap = kk >> 3;       c = 32 + (kk & 7); }
        else if (s == 10){ tap = 4 + (kk >> 3); c = 32 + (kk & 7); }
        else             { tap = 8;             c = 32 + (kk & 7); ok = (kk < 8); }
        float v = (ok && c < CIN) ? w1[(o * CIN + c) * 9 + tap] : 0.f;
        w1m[idx] = f2bf(v);
        return;
    }
    int j = idx - 24576;
    if (j >= 0 && j < 18432) {
        int kk = j & 31, oc = (j >> 5) & 31, s = j >> 10;
        int tap = s >> 1, c = (s & 1) * 32 + kk;
        float v = 0.f;
        if (oc < 18)      v = wo[(oc * 64 + c) * 9 + tap];
        else if (oc < 27) v = wm[((oc - 18) * 64 + c) * 9 + tap];
        wcm[j] = f2bf(v);
        return;
    }
    int m = idx - 24576 - 18432;
    if (m >= 0 && m < 36864) {
        int c = m & 63, o = (m >> 6) & 63, k = m >> 12;
        wdt16[m] = f2bf(wd[(o * 64 + c) * 9 + k]);
    }
}

// ---------------- conv1 (39->64) MFMA + ReLU + BN1 stats ----------------------
__global__ __launch_bounds__(256, 4) void conv1_mfma(
        const float* __restrict__ xg, const float* __restrict__ b1,
        const unsigned short* __restrict__ w1m, float* __restrict__ h1,
        float* __restrict__ sum1, float* __restrict__ sq1) {
    __shared__ short xs[128 * 64];   // [r(121)][c(64)] bf16, byte ^= (r&7)<<4
    int b = blockIdx.x, t = threadIdx.x;
    for (int i = t; i < 4096; i += 256) ((unsigned*)xs)[i] = 0u;
    __syncthreads();
    const float* xb = xg + (size_t)b * (HW * CIN);
    const float4* xb4 = (const float4*)xb;
    for (int i4 = t; i4 < 789; i4 += 256) {
        float4 v = xb4[i4];
        float vv[4] = { v.x, v.y, v.z, v.w };
        int base = 4 * i4;
#pragma unroll
        for (int k = 0; k < 4; ++k) {
            int idx = base + k;
            int p = idx / 39, c = idx - 39 * p;
            int y = p / 9, xx = p - 9 * y;
            int r = (y + 1) * 11 + xx + 1;
            int byte = r * 128 + ((c * 2) ^ ((r & 7) << 4));
            xs[byte >> 1] = (short)f2bf(vv[k]);
        }
    }
    if (t < 3) {
        int idx = 3156 + t;
        int p = idx / 39, c = idx - 39 * p;
        int y = p / 9, xx = p - 9 * y;
        int r = (y + 1) * 11 + xx + 1;
        int byte = r * 128 + ((c * 2) ^ ((r & 7) << 4));
        xs[byte >> 1] = (short)f2bf(xb[idx]);
    }
    __syncthreads();
    int lane = t & 63, wv = t >> 6, lg = lane >> 4, lr = lane & 15;
    int o = wv * 16 + lr;
    floatx4 acc[6];
#pragma unroll
    for (int n = 0; n < 6; ++n) acc[n] = (floatx4)0.f;
    int rbn[6];
#pragma unroll
    for (int n = 0; n < 6; ++n) {
        int p = n * 16 + lr; p = p > 80 ? 80 : p;
        int y = p / 9, xx = p - 9 * y;
        rbn[n] = (y + 1) * 11 + xx + 1;
    }
#pragma unroll
    for (int s = 0; s < 12; ++s) {
        bfrag8 a = *(const bfrag8*)&w1m[(s * 64 + o) * 32 + lg * 8];
        int roff, cb;
        if (s < 9)       { roff = (s / 3 - 1) * 11 + (s % 3) - 1; cb = lg * 16; }
        else if (s == 9) { roff = (lg / 3 - 1) * 11 + (lg % 3) - 1; cb = 64; }
        else if (s == 10){ int tp = lg + 4; roff = (tp / 3 - 1) * 11 + (tp % 3) - 1; cb = 64; }
        else             { roff = 12; cb = 64; }
#pragma unroll
        for (int n = 0; n < 6; ++n) {
            int r = rbn[n] + roff;
            int byte = r * 128 + (cb ^ ((r & 7) << 4));
            bfrag8 bf = *(const bfrag8*)((const char*)xs + byte);
            acc[n] = __builtin_amdgcn_mfma_f32_16x16x32_bf16(a, bf, acc[n], 0, 0, 0);
        }
    }
    float* h1b = h1 + (size_t)b * 5184;
    int bucket = (b & 31) << 6;
#pragma unroll
    for (int j = 0; j < 4; ++j) {
        int oo = wv * 16 + lg * 4 + j;
        float bias = b1[oo];
        float ss = 0.f, qq = 0.f;
#pragma unroll
        for (int n = 0; n < 6; ++n) {
            int p = n * 16 + lr;
            float v = fmaxf(acc[n][j] + bias, 0.f);
            if (p < 81) { h1b[oo * 81 + p] = v; ss += v; qq += v * v; }
        }
#pragma unroll
        for (int off = 1; off < 16; off <<= 1) { ss += __shfl_xor(ss, off); qq += __shfl_xor(qq, off); }
        if (lr == 0) { atomicAdd(&sum1[bucket + oo], ss); atomicAdd(&sq1[bucket + oo], qq); }
    }
}

// ---------------- BN2 finalize + apply (fused; aligned float4 body) -----------
__global__ __launch_bounds__(256) void bn_apply2(
        float* __restrict__ data, const float* __restrict__ sums,
        const float* __restrict__ sqs, const float* __restrict__ gamma,
        const float* __restrict__ beta, int n, float* __restrict__ dout) {
    __shared__ float sc[64], sh[64];
    int t = threadIdx.x;
    if (t < 64) {
        float s = 0.f, q = 0.f;
#pragma unroll
        for (int r = 0; r < 32; ++r) { s += sums[(r << 6) + t]; q += sqs[(r << 6) + t]; }
        float m = s / (float)NPIX;
        float v = q / (float)NPIX - m * m;
        float scv = gamma[t] * (1.f / sqrtf(v + 1e-5f));
        sc[t] = scv; sh[t] = beta[t] - m * scv;
    }
    __syncthreads();
    if (blockIdx.x == 0) {
        if (t == 0) dout[0] = 0.5f;
        if (t < 3) data[t] = data[t] * sc[0] + sh[0];   // e<81 -> c=0
        if (t == 3) {
            int e = n - 1;
            int c = (e / 81) & 63;
            data[e] = data[e] * sc[c] + sh[c];
        }
    }
    float4* d4 = (float4*)(data + 3);
    int n4 = (n - 4) >> 2;    // covers elements 3 .. n-2
    for (int i = blockIdx.x * 256 + t; i < n4; i += gridDim.x * 256) {
        float4 v = d4[i];
        unsigned e = 3u + 4u * (unsigned)i;
        int c0 = (int)((e) / 81u) & 63;
        int c1 = (int)((e + 1) / 81u) & 63;
        int c2 = (int)((e + 2) / 81u) & 63;
        int c3 = (int)((e + 3) / 81u) & 63;
        v.x = v.x * sc[c0] + sh[c0];
        v.y = v.y * sc[c1] + sh[c1];
        v.z = v.z * sc[c2] + sh[c2];
        v.w = v.w * sc[c3] + sh[c3];
        d4[i] = v;
    }
}

// ---------------- FUSED offset/mask conv + deformable conv (MFMA) --------------
// r19 structure exactly; LDS shrunk 40496 -> 39984 (alloc 40448, 4x = 161792)
// by aliasing sc1/sh1 onto the first 512B of the bwt region (lifetimes
// disjoint: sc1/sh1 read only in P0; bwt written only in P2, two barriers
// later). Goal: unblock the 4th resident block/CU.
//   hsh [0,20736)      f32 [q][256B], byte q*256 + ((c*4)^((q&15)<<4))
//   bwt [20736,26568)  uint2[729]  (first 512B = sc1/sh1 during P0)
//   bix [26568,29484)  uint[729]
//   xs/om/vt [29488,39984) xs bf16 [r(82)][128B] (P0/P1, row 81 zeros);
//                       om f32[1458]+omm f32[729] (P1 epi..P2); vt (fills)
__global__ __launch_bounds__(256, 4) void offdeform_mfma(
        const float* __restrict__ h1, const unsigned short* __restrict__ wcm,
        const unsigned short* __restrict__ wdt16,
        const float* __restrict__ bo, const float* __restrict__ bm,
        const float* __restrict__ bd,
        const float* __restrict__ sum1, const float* __restrict__ sq1,
        const float* __restrict__ g1, const float* __restrict__ be1,
        float* __restrict__ dout, float* __restrict__ sum2, float* __restrict__ sq2) {
    __shared__ __align__(16) char L[39984];
    float*    hsh = (float*)L;
    uint2*    bwt = (uint2*)(L + 20736);
    unsigned* bix = (unsigned*)(L + 26568);
    char*     vtb = L + 29488;               // xs (P0/P1) -> om/omm (P1..P2) -> vt
    float*    om  = (float*)(L + 29488);     // 1458 f32
    float*    omm = (float*)(L + 29488) + 1458; // 729 f32
    float*    sc1 = (float*)(L + 20736);     // alias bwt[0..64)   (P0 only)
    float*    sh1 = (float*)(L + 20992);     // alias bwt[64..128) (P0 only)

    int b = blockIdx.x, t = threadIdx.x;
    int lane = t & 63, wv = t >> 6, lg = lane >> 4, lr = lane & 15;

    // ---- BN1 finalize folded in (per block, cheap)
    if (t < 64) {
        float s = 0.f, q = 0.f;
#pragma unroll
        for (int r = 0; r < 32; ++r) { s += sum1[(r << 6) + t]; q += sq1[(r << 6) + t]; }
        float m = s / (float)NPIX;
        float v = q / (float)NPIX - m * m;
        float scv = g1[t] * (1.f / sqrtf(v + 1e-5f));
        sc1[t] = scv; sh1[t] = be1[t] - m * scv;
    }
    __syncthreads();

    // ---- P0: stage h as f32 hsh (swizzled) + bf16 xs (vt layout), BN1 folded
    const float* hb = h1 + (size_t)b * 5184;
    for (int i = t; i < 2592; i += 256) {
        int c2 = i / 81, q = i - c2 * 81;
        int c = 2 * c2;
        float va = hb[c * 81 + q]      * sc1[c]     + sh1[c];
        float vb = hb[c * 81 + 81 + q] * sc1[c + 1] + sh1[c + 1];
        *(float2*)((char*)hsh + q * 256 + ((c * 4) ^ ((q & 15) << 4))) = make_float2(va, vb);
        unsigned pk;
        asm("v_cvt_pk_bf16_f32 %0, %1, %2" : "=v"(pk) : "v"(va), "v"(vb));
        *(unsigned*)(vtb + q * 128 + ((c * 2) ^ ((q & 7) << 4))) = pk;
    }
    if (t < 32) *(unsigned*)(vtb + 81 * 128 + t * 4) = 0u;   // zero row 81
    __syncthreads();

    // ---- P1: offset/mask GEMM; OOB fragments -> zero row (no select)
    int mt = wv >> 1, nh = (wv & 1) * 3;
    int ocr = mt * 16 + lr;
    floatx4 oacc[3];
#pragma unroll
    for (int n = 0; n < 3; ++n) oacc[n] = (floatx4)0.f;
    int yn[3], xn[3];
#pragma unroll
    for (int ni = 0; ni < 3; ++ni) {
        int p = (nh + ni) * 16 + lr; p = p > 80 ? 80 : p;
        yn[ni] = p / 9; xn[ni] = p - 9 * yn[ni];
    }
#pragma unroll
    for (int s = 0; s < 18; ++s) {
        const int tap = s >> 1, dyk = tap / 3 - 1, dxk = tap % 3 - 1;
        const int cb1 = (s & 1) * 64 + lg * 16;
        bfrag8 af = *(const bfrag8*)&wcm[(s * 32 + ocr) * 32 + lg * 8];
#pragma unroll
        for (int ni = 0; ni < 3; ++ni) {
            int yy = yn[ni] + dyk, xx2 = xn[ni] + dxk;
            bool val = ((unsigned)yy < 9u) & ((unsigned)xx2 < 9u);
            int q2 = val ? yy * 9 + xx2 : 81;
            bfrag8 bf = *(const bfrag8*)(vtb + q2 * 128 + (cb1 ^ ((q2 & 7) << 4)));
            oacc[ni] = __builtin_amdgcn_mfma_f32_16x16x32_bf16(af, bf, oacc[ni], 0, 0, 0);
        }
    }
    __syncthreads();   // ALL waves done reading xs before om/omm overwrite it

    // P1 epilogue: offsets -> dout (output) + om (LDS); mask -> omm (LDS)
#pragma unroll
    for (int j = 0; j < 4; ++j) {
        int oc = mt * 16 + lg * 4 + j;
        if (oc < 18) {
            float bias = bo[oc];
            float* ob = dout + OUT_OFF_BASE + (size_t)b * 1458 + oc * 81;
#pragma unroll
            for (int ni = 0; ni < 3; ++ni) {
                int p = (nh + ni) * 16 + lr;
                if (p < 81) { float v = oacc[ni][j] + bias; ob[p] = v; om[oc * 81 + p] = v; }
            }
        } else if (oc < 27) {
            float bias = bm[oc - 18];
#pragma unroll
            for (int ni = 0; ni < 3; ++ni) {
                int p = (nh + ni) * 16 + lr;
                if (p < 81) { float v = oacc[ni][j] + bias; omm[(oc - 18) * 81 + p] = 1.f / (1.f + expf(-v)); }
            }
        }
    }
    __syncthreads();   // om/omm visible to all waves

    // ---- P2: bilinear params per (tap,pixel) from LDS om/omm -> bwt/bix
    for (int i = t; i < 729; i += 256) {
        int k = i / 81, p = i - k * 81;
        float dy = om[(2 * k) * 81 + p];
        float dx = om[(2 * k + 1) * 81 + p];
        float m  = omm[i];
        int y = p / 9, xx = p - y * 9;
        float py = dy + (float)(y + k / 3 - 1);
        float px = dx + (float)(xx + (k % 3) - 1);
        float fy = floorf(py), fx = floorf(px);
        float ly = py - fy, lx = px - fx;
        int y0 = (int)fy, x0 = (int)fx;
        int y1 = y0 + 1, x1 = x0 + 1;
        bool vy0 = (y0 >= 0) & (y0 < 9), vy1 = (y1 >= 0) & (y1 < 9);
        bool vx0 = (x0 >= 0) & (x0 < 9), vx1 = (x1 >= 0) & (x1 < 9);
        float w00 = (vy0 && vx0) ? m * (1.f - ly) * (1.f - lx) : 0.f;
        float w01 = (vy0 && vx1) ? m * (1.f - ly) * lx : 0.f;
        float w10 = (vy1 && vx0) ? m * ly * (1.f - lx) : 0.f;
        float w11 = (vy1 && vx1) ? m * ly * lx : 0.f;
        int yc0 = min(max(y0, 0), 8), yc1 = min(max(y1, 0), 8);
        int xc0 = min(max(x0, 0), 8), xc1 = min(max(x1, 0), 8);
        unsigned q00 = yc0 * 9 + xc0, q01 = yc0 * 9 + xc1;
        unsigned q10 = yc1 * 9 + xc0, q11 = yc1 * 9 + xc1;
        bwt[i] = make_uint2((unsigned)f2bf(w00) | ((unsigned)f2bf(w01) << 16),
                            (unsigned)f2bf(w10) | ((unsigned)f2bf(w11) << 16));
        bix[i] = q00 | (q01 << 8) | (q10 << 16) | (q11 << 24);
    }
    __syncthreads();   // params visible; om/omm dead; vt region free for fills

    // ---- fill tap kk into vt: 648 half-slots (81 p x 8 16B-chunks)
    auto stage_tap = [&](int kk) {
        int kbase = kk * 81;
        const char* hc = (const char*)hsh;
#pragma unroll
        for (int j2 = 0; j2 < 3; ++j2) {
            int s = t + j2 * 256;
            if (j2 == 2 && s >= 648) break;
            int gg = s & 7, p = s >> 3;
            uint2 bw = bwt[kbase + p];
            unsigned ix = bix[kbase + p];
            float w00 = bfhi2f(bw.x << 16), w01 = bfhi2f(bw.x & 0xffff0000u);
            float w10 = bfhi2f(bw.y << 16), w11 = bfhi2f(bw.y & 0xffff0000u);
            unsigned q00 = ix & 255u, q01 = (ix >> 8) & 255u;
            unsigned q10 = (ix >> 16) & 255u, q11 = ix >> 24;
            int b00 = (int)((q00 << 8) | ((q00 & 15u) << 4));
            int b01 = (int)((q01 << 8) | ((q01 & 15u) << 4));
            int b10 = (int)((q10 << 8) | ((q10 & 15u) << 4));
            int b11 = (int)((q11 << 8) | ((q11 & 15u) << 4));
            unsigned res[4];
#pragma unroll
            for (int jj = 0; jj < 2; ++jj) {
                int off = gg * 32 + jj * 16;
                floatx4 a4 = *(const floatx4*)(hc + (b00 ^ off)) * w00;
                a4 += *(const floatx4*)(hc + (b01 ^ off)) * w01;
                a4 += *(const floatx4*)(hc + (b10 ^ off)) * w10;
                a4 += *(const floatx4*)(hc + (b11 ^ off)) * w11;
                unsigned pk0, pk1;
                asm("v_cvt_pk_bf16_f32 %0, %1, %2" : "=v"(pk0) : "v"(a4.x), "v"(a4.y));
                asm("v_cvt_pk_bf16_f32 %0, %1, %2" : "=v"(pk1) : "v"(a4.z), "v"(a4.w));
                res[2 * jj] = pk0; res[2 * jj + 1] = pk1;
            }
            int swzv = (p & 7) << 4;
            *(uint4*)(vtb + p * 128 + ((gg * 16) ^ swzv)) = make_uint4(res[0], res[1], res[2], res[3]);
        }
    };

    // ---- deform GEMM: wave = (m-pair mh) x (n-half nh2)
    int mh = wv >> 1, nh2 = wv & 1;
    int o0 = (2 * mh) * 16 + lr;
    int o1 = (2 * mh + 1) * 16 + lr;
    floatx4 accA[3], accB[3];
#pragma unroll
    for (int n = 0; n < 3; ++n) { accA[n] = (floatx4)0.f; accB[n] = (floatx4)0.f; }
    int rowb[3], swzn[3];
#pragma unroll
    for (int n = 0; n < 3; ++n) {
        int row = (nh2 * 3 + n) * 16 + lr; row = row > 80 ? 80 : row;
        rowb[n] = row * 128;
        swzn[n] = (row & 7) << 4;
    }

#pragma unroll
    for (int k = 0; k < 9; ++k) {
        stage_tap(k);
        __syncthreads();
        bfrag8 A00 = *(const bfrag8*)&wdt16[(k * 64 + o0) * 64 + lg * 8];
        bfrag8 A01 = *(const bfrag8*)&wdt16[(k * 64 + o0) * 64 + 32 + lg * 8];
        bfrag8 A10 = *(const bfrag8*)&wdt16[(k * 64 + o1) * 64 + lg * 8];
        bfrag8 A11 = *(const bfrag8*)&wdt16[(k * 64 + o1) * 64 + 32 + lg * 8];
        const char* vb = (const char*)vtb;
#pragma unroll
        for (int n = 0; n < 3; ++n) {
            bfrag8 b0 = *(const bfrag8*)(vb + rowb[n] + ((lg * 16) ^ swzn[n]));
            bfrag8 b1 = *(const bfrag8*)(vb + rowb[n] + ((64 + lg * 16) ^ swzn[n]));
            accA[n] = __builtin_amdgcn_mfma_f32_16x16x32_bf16(A00, b0, accA[n], 0, 0, 0);
            accA[n] = __builtin_amdgcn_mfma_f32_16x16x32_bf16(A01, b1, accA[n], 0, 0, 0);
            accB[n] = __builtin_amdgcn_mfma_f32_16x16x32_bf16(A10, b0, accB[n], 0, 0, 0);
            accB[n] = __builtin_amdgcn_mfma_f32_16x16x32_bf16(A11, b1, accB[n], 0, 0, 0);
        }
        if (k < 8) __syncthreads();
    }

    // ---- epilogue: bias, pre-BN output, BN2 stats (replicated buckets)
    float* outb = dout + OUT_H_BASE + (size_t)b * 5184;
    int bucket = (b & 31) << 6;
#pragma unroll
    for (int mm = 0; mm < 2; ++mm) {
#pragma unroll
        for (int j = 0; j < 4; ++j) {
            int oo = (2 * mh + mm) * 16 + lg * 4 + j;
            float bias = bd[oo];
            float ss = 0.f, qq = 0.f;
#pragma unroll
            for (int n = 0; n < 3; ++n) {
                int p = (nh2 * 3 + n) * 16 + lr;
                float v = (mm == 0 ? accA[n][j] : accB[n][j]) + bias;
                if (p < 81) { outb[oo * 81 + p] = v; ss += v; qq += v * v; }
            }
#pragma unroll
            for (int off = 1; off < 16; off <<= 1) {
                ss += __shfl_xor(ss, off);
                qq += __shfl_xor(qq, off);
            }
            if (lr == 0) { atomicAdd(&sum2[bucket + oo], ss); atomicAdd(&sq2[bucket + oo], qq); }
        }
    }
}

// ---------------- launch -------------------------------------------------------
extern "C" void kernel_launch(void* const* d_in, const int* in_sizes, int n_in,
                              void* d_out, int out_size, void* d_ws, size_t ws_size,
                              hipStream_t stream) {
    const float* x   = (const float*)d_in[0];
    const float* w1  = (const float*)d_in[1];
    const float* b1  = (const float*)d_in[2];
    const float* g1  = (const float*)d_in[3];
    const float* be1 = (const float*)d_in[4];
    const float* wo  = (const float*)d_in[5];
    const float* bo  = (const float*)d_in[6];
    const float* wm  = (const float*)d_in[7];
    const float* bm  = (const float*)d_in[8];
    const float* wd  = (const float*)d_in[9];
    const float* bd  = (const float*)d_in[10];
    const float* g2  = (const float*)d_in[11];
    const float* be2 = (const float*)d_in[12];
    float* dout = (float*)d_out;
    float* ws   = (float*)d_ws;

    float* h1    = ws + WS_H1;
    const unsigned short* wdt16 = (const unsigned short*)(ws + WS_WDT);
    const unsigned short* w1m   = (const unsigned short*)(ws + WS_W1M);
    const unsigned short* wcm   = (const unsigned short*)(ws + WS_WCM);
    float* stats = ws + WS_STATS;
    float* sum1 = stats,        *sq1 = stats + 2048;
    float* sum2 = stats + 4096, *sq2 = stats + 6144;

    // zero the replicated BN accumulators (ws is NOT re-poisoned between replays)
    hipMemsetAsync(stats, 0, 8192 * sizeof(float), stream);

    prep_weights<<<312, 256, 0, stream>>>(w1, wo, wm, wd, ws);
    conv1_mfma<<<BATCH, 256, 0, stream>>>(x, b1, w1m, h1, sum1, sq1);
    offdeform_mfma<<<BATCH, 256, 0, stream>>>(h1, wcm, wdt16, bo, bm, bd,
                                              sum1, sq1, g1, be1, dout, sum2, sq2);
    bn_apply2<<<2048, 256, 0, stream>>>(dout + OUT_H_BASE, sum2, sq2, g2, be2,
                                        BATCH * 5184, dout);
}

// Round 21
// 126.446 us; speedup vs baseline: 1.0189x; 1.0189x over previous
//
#include <hip/hip_runtime.h>
#include <hip/hip_bf16.h>

// Problem constants
#define BATCH   2048
#define HW      81          // 9x9
#define CIN     39
#define NPIX    (BATCH*HW)  // 165888

// ws layout (float offsets)
#define WS_H1     0              // 10,616,832 floats  (B,64,81)  PRE-BN h
#define WS_WDT    12109824       // 36,864 ushort bf16 [k][o][c]   (18,432 floats)
#define WS_W1M    12128256       // 24,576 ushort bf16 [12][64][32] (12,288 floats)
#define WS_WCM    12140544       // 18,432 ushort bf16 [18][32][32] (9,216 floats)
#define WS_STATS  12149760       // 8192 floats: sum1[2048],sq1[2048],sum2[2048],sq2[2048]

#define OUT_OFF_BASE 1
#define OUT_H_BASE   (1 + BATCH*18*81)   // 2985985

typedef __attribute__((ext_vector_type(8))) short bfrag8;
typedef __attribute__((ext_vector_type(4))) float floatx4;

__device__ __forceinline__ unsigned short f2bf(float f) {
    unsigned u = __builtin_bit_cast(unsigned, f);
    u += 0x7FFFu + ((u >> 16) & 1u);       // round-to-nearest-even
    return (unsigned short)(u >> 16);
}
__device__ __forceinline__ float bfhi2f(unsigned hi16) {   // hi16 already in bits 31..16
    return __builtin_bit_cast(float, hi16);
}

// ---------------- weight prep: fragment-ready bf16 layouts --------------------
__global__ void prep_weights(const float* __restrict__ w1, const float* __restrict__ wo,
                             const float* __restrict__ wm, const float* __restrict__ wd,
                             float* __restrict__ ws) {
    int idx = blockIdx.x * 256 + threadIdx.x;
    unsigned short* w1m = (unsigned short*)(ws + WS_W1M);
    unsigned short* wcm = (unsigned short*)(ws + WS_WCM);
    unsigned short* wdt16 = (unsigned short*)(ws + WS_WDT);
    if (idx < 24576) {
        int kk = idx & 31, o = (idx >> 5) & 63, s = idx >> 11;
        int tap, c; bool ok = true;
        if (s < 9)       { tap = s;             c = kk; }
        else if (s == 9) { tap = kk >> 3;       c = 32 + (kk & 7); }
        else if (s == 10){ tap = 4 + (kk >> 3); c = 32 + (kk & 7); }
        else             { tap = 8;             c = 32 + (kk & 7); ok = (kk < 8); }
        float v = (ok && c < CIN) ? w1[(o * CIN + c) * 9 + tap] : 0.f;
        w1m[idx] = f2bf(v);
        return;
    }
    int j = idx - 24576;
    if (j >= 0 && j < 18432) {
        int kk = j & 31, oc = (j >> 5) & 31, s = j >> 10;
        int tap = s >> 1, c = (s & 1) * 32 + kk;
        float v = 0.f;
        if (oc < 18)      v = wo[(oc * 64 + c) * 9 + tap];
        else if (oc < 27) v = wm[((oc - 18) * 64 + c) * 9 + tap];
        wcm[j] = f2bf(v);
        return;
    }
    int m = idx - 24576 - 18432;
    if (m >= 0 && m < 36864) {
        int c = m & 63, o = (m >> 6) & 63, k = m >> 12;
        wdt16[m] = f2bf(wd[(o * 64 + c) * 9 + k]);
    }
}

// ---------------- conv1 (39->64) MFMA + ReLU + BN1 stats ----------------------
__global__ __launch_bounds__(256, 4) void conv1_mfma(
        const float* __restrict__ xg, const float* __restrict__ b1,
        const unsigned short* __restrict__ w1m, float* __restrict__ h1,
        float* __restrict__ sum1, float* __restrict__ sq1) {
    __shared__ short xs[128 * 64];   // [r(121)][c(64)] bf16, byte ^= (r&7)<<4
    int b = blockIdx.x, t = threadIdx.x;
    for (int i = t; i < 4096; i += 256) ((unsigned*)xs)[i] = 0u;
    __syncthreads();
    const float* xb = xg + (size_t)b * (HW * CIN);
    const float4* xb4 = (const float4*)xb;
    for (int i4 = t; i4 < 789; i4 += 256) {
        float4 v = xb4[i4];
        float vv[4] = { v.x, v.y, v.z, v.w };
        int base = 4 * i4;
#pragma unroll
        for (int k = 0; k < 4; ++k) {
            int idx = base + k;
            int p = idx / 39, c = idx - 39 * p;
            int y = p / 9, xx = p - 9 * y;
            int r = (y + 1) * 11 + xx + 1;
            int byte = r * 128 + ((c * 2) ^ ((r & 7) << 4));
            xs[byte >> 1] = (short)f2bf(vv[k]);
        }
    }
    if (t < 3) {
        int idx = 3156 + t;
        int p = idx / 39, c = idx - 39 * p;
        int y = p / 9, xx = p - 9 * y;
        int r = (y + 1) * 11 + xx + 1;
        int byte = r * 128 + ((c * 2) ^ ((r & 7) << 4));
        xs[byte >> 1] = (short)f2bf(xb[idx]);
    }
    __syncthreads();
    int lane = t & 63, wv = t >> 6, lg = lane >> 4, lr = lane & 15;
    int o = wv * 16 + lr;
    floatx4 acc[6];
#pragma unroll
    for (int n = 0; n < 6; ++n) acc[n] = (floatx4)0.f;
    int rbn[6];
#pragma unroll
    for (int n = 0; n < 6; ++n) {
        int p = n * 16 + lr; p = p > 80 ? 80 : p;
        int y = p / 9, xx = p - 9 * y;
        rbn[n] = (y + 1) * 11 + xx + 1;
    }
#pragma unroll
    for (int s = 0; s < 12; ++s) {
        bfrag8 a = *(const bfrag8*)&w1m[(s * 64 + o) * 32 + lg * 8];
        int roff, cb;
        if (s < 9)       { roff = (s / 3 - 1) * 11 + (s % 3) - 1; cb = lg * 16; }
        else if (s == 9) { roff = (lg / 3 - 1) * 11 + (lg % 3) - 1; cb = 64; }
        else if (s == 10){ int tp = lg + 4; roff = (tp / 3 - 1) * 11 + (tp % 3) - 1; cb = 64; }
        else             { roff = 12; cb = 64; }
#pragma unroll
        for (int n = 0; n < 6; ++n) {
            int r = rbn[n] + roff;
            int byte = r * 128 + (cb ^ ((r & 7) << 4));
            bfrag8 bf = *(const bfrag8*)((const char*)xs + byte);
            acc[n] = __builtin_amdgcn_mfma_f32_16x16x32_bf16(a, bf, acc[n], 0, 0, 0);
        }
    }
    float* h1b = h1 + (size_t)b * 5184;
    int bucket = (b & 31) << 6;
#pragma unroll
    for (int j = 0; j < 4; ++j) {
        int oo = wv * 16 + lg * 4 + j;
        float bias = b1[oo];
        float ss = 0.f, qq = 0.f;
#pragma unroll
        for (int n = 0; n < 6; ++n) {
            int p = n * 16 + lr;
            float v = fmaxf(acc[n][j] + bias, 0.f);
            if (p < 81) { h1b[oo * 81 + p] = v; ss += v; qq += v * v; }
        }
#pragma unroll
        for (int off = 1; off < 16; off <<= 1) { ss += __shfl_xor(ss, off); qq += __shfl_xor(qq, off); }
        if (lr == 0) { atomicAdd(&sum1[bucket + oo], ss); atomicAdd(&sq1[bucket + oo], qq); }
    }
}

// ---------------- BN2 finalize + apply (fused; aligned float4 body) -----------
__global__ __launch_bounds__(256) void bn_apply2(
        float* __restrict__ data, const float* __restrict__ sums,
        const float* __restrict__ sqs, const float* __restrict__ gamma,
        const float* __restrict__ beta, int n, float* __restrict__ dout) {
    __shared__ float sc[64], sh[64];
    int t = threadIdx.x;
    if (t < 64) {
        float s = 0.f, q = 0.f;
#pragma unroll
        for (int r = 0; r < 32; ++r) { s += sums[(r << 6) + t]; q += sqs[(r << 6) + t]; }
        float m = s / (float)NPIX;
        float v = q / (float)NPIX - m * m;
        float scv = gamma[t] * (1.f / sqrtf(v + 1e-5f));
        sc[t] = scv; sh[t] = beta[t] - m * scv;
    }
    __syncthreads();
    if (blockIdx.x == 0) {
        if (t == 0) dout[0] = 0.5f;
        if (t < 3) data[t] = data[t] * sc[0] + sh[0];   // e<81 -> c=0
        if (t == 3) {
            int e = n - 1;
            int c = (e / 81) & 63;
            data[e] = data[e] * sc[c] + sh[c];
        }
    }
    float4* d4 = (float4*)(data + 3);
    int n4 = (n - 4) >> 2;    // covers elements 3 .. n-2
    for (int i = blockIdx.x * 256 + t; i < n4; i += gridDim.x * 256) {
        float4 v = d4[i];
        unsigned e = 3u + 4u * (unsigned)i;
        int c0 = (int)((e) / 81u) & 63;
        int c1 = (int)((e + 1) / 81u) & 63;
        int c2 = (int)((e + 2) / 81u) & 63;
        int c3 = (int)((e + 3) / 81u) & 63;
        v.x = v.x * sc[c0] + sh[c0];
        v.y = v.y * sc[c1] + sh[c1];
        v.z = v.z * sc[c2] + sh[c2];
        v.w = v.w * sc[c3] + sh[c3];
        d4[i] = v;
    }
}

// ---------------- FUSED offset/mask conv + deformable conv (MFMA) --------------
// r20 structure exactly + T5: s_setprio(1) around the deform MFMA cluster.
// Resident blocks are phase-staggered (fill vs MFMA), so priority arbitration
// between blocks' waves on the same SIMD can favor the matrix pipe.
//   hsh [0,20736)      f32 [q][256B], byte q*256 + ((c*4)^((q&15)<<4))
//   bwt [20736,26568)  uint2[729]  (first 512B = sc1/sh1 during P0)
//   bix [26568,29484)  uint[729]
//   xs/om/vt [29488,39984) xs bf16 [r(82)][128B] (P0/P1, row 81 zeros);
//                       om f32[1458]+omm f32[729] (P1 epi..P2); vt (fills)
__global__ __launch_bounds__(256, 4) void offdeform_mfma(
        const float* __restrict__ h1, const unsigned short* __restrict__ wcm,
        const unsigned short* __restrict__ wdt16,
        const float* __restrict__ bo, const float* __restrict__ bm,
        const float* __restrict__ bd,
        const float* __restrict__ sum1, const float* __restrict__ sq1,
        const float* __restrict__ g1, const float* __restrict__ be1,
        float* __restrict__ dout, float* __restrict__ sum2, float* __restrict__ sq2) {
    __shared__ __align__(16) char L[39984];
    float*    hsh = (float*)L;
    uint2*    bwt = (uint2*)(L + 20736);
    unsigned* bix = (unsigned*)(L + 26568);
    char*     vtb = L + 29488;               // xs (P0/P1) -> om/omm (P1..P2) -> vt
    float*    om  = (float*)(L + 29488);     // 1458 f32
    float*    omm = (float*)(L + 29488) + 1458; // 729 f32
    float*    sc1 = (float*)(L + 20736);     // alias bwt[0..64)   (P0 only)
    float*    sh1 = (float*)(L + 20992);     // alias bwt[64..128) (P0 only)

    int b = blockIdx.x, t = threadIdx.x;
    int lane = t & 63, wv = t >> 6, lg = lane >> 4, lr = lane & 15;

    // ---- BN1 finalize folded in (per block, cheap)
    if (t < 64) {
        float s = 0.f, q = 0.f;
#pragma unroll
        for (int r = 0; r < 32; ++r) { s += sum1[(r << 6) + t]; q += sq1[(r << 6) + t]; }
        float m = s / (float)NPIX;
        float v = q / (float)NPIX - m * m;
        float scv = g1[t] * (1.f / sqrtf(v + 1e-5f));
        sc1[t] = scv; sh1[t] = be1[t] - m * scv;
    }
    __syncthreads();

    // ---- P0: stage h as f32 hsh (swizzled) + bf16 xs (vt layout), BN1 folded
    const float* hb = h1 + (size_t)b * 5184;
    for (int i = t; i < 2592; i += 256) {
        int c2 = i / 81, q = i - c2 * 81;
        int c = 2 * c2;
        float va = hb[c * 81 + q]      * sc1[c]     + sh1[c];
        float vb = hb[c * 81 + 81 + q] * sc1[c + 1] + sh1[c + 1];
        *(float2*)((char*)hsh + q * 256 + ((c * 4) ^ ((q & 15) << 4))) = make_float2(va, vb);
        unsigned pk;
        asm("v_cvt_pk_bf16_f32 %0, %1, %2" : "=v"(pk) : "v"(va), "v"(vb));
        *(unsigned*)(vtb + q * 128 + ((c * 2) ^ ((q & 7) << 4))) = pk;
    }
    if (t < 32) *(unsigned*)(vtb + 81 * 128 + t * 4) = 0u;   // zero row 81
    __syncthreads();

    // ---- P1: offset/mask GEMM; OOB fragments -> zero row (no select)
    int mt = wv >> 1, nh = (wv & 1) * 3;
    int ocr = mt * 16 + lr;
    floatx4 oacc[3];
#pragma unroll
    for (int n = 0; n < 3; ++n) oacc[n] = (floatx4)0.f;
    int yn[3], xn[3];
#pragma unroll
    for (int ni = 0; ni < 3; ++ni) {
        int p = (nh + ni) * 16 + lr; p = p > 80 ? 80 : p;
        yn[ni] = p / 9; xn[ni] = p - 9 * yn[ni];
    }
#pragma unroll
    for (int s = 0; s < 18; ++s) {
        const int tap = s >> 1, dyk = tap / 3 - 1, dxk = tap % 3 - 1;
        const int cb1 = (s & 1) * 64 + lg * 16;
        bfrag8 af = *(const bfrag8*)&wcm[(s * 32 + ocr) * 32 + lg * 8];
#pragma unroll
        for (int ni = 0; ni < 3; ++ni) {
            int yy = yn[ni] + dyk, xx2 = xn[ni] + dxk;
            bool val = ((unsigned)yy < 9u) & ((unsigned)xx2 < 9u);
            int q2 = val ? yy * 9 + xx2 : 81;
            bfrag8 bf = *(const bfrag8*)(vtb + q2 * 128 + (cb1 ^ ((q2 & 7) << 4)));
            oacc[ni] = __builtin_amdgcn_mfma_f32_16x16x32_bf16(af, bf, oacc[ni], 0, 0, 0);
        }
    }
    __syncthreads();   // ALL waves done reading xs before om/omm overwrite it

    // P1 epilogue: offsets -> dout (output) + om (LDS); mask -> omm (LDS)
#pragma unroll
    for (int j = 0; j < 4; ++j) {
        int oc = mt * 16 + lg * 4 + j;
        if (oc < 18) {
            float bias = bo[oc];
            float* ob = dout + OUT_OFF_BASE + (size_t)b * 1458 + oc * 81;
#pragma unroll
            for (int ni = 0; ni < 3; ++ni) {
                int p = (nh + ni) * 16 + lr;
                if (p < 81) { float v = oacc[ni][j] + bias; ob[p] = v; om[oc * 81 + p] = v; }
            }
        } else if (oc < 27) {
            float bias = bm[oc - 18];
#pragma unroll
            for (int ni = 0; ni < 3; ++ni) {
                int p = (nh + ni) * 16 + lr;
                if (p < 81) { float v = oacc[ni][j] + bias; omm[(oc - 18) * 81 + p] = 1.f / (1.f + expf(-v)); }
            }
        }
    }
    __syncthreads();   // om/omm visible to all waves

    // ---- P2: bilinear params per (tap,pixel) from LDS om/omm -> bwt/bix
    for (int i = t; i < 729; i += 256) {
        int k = i / 81, p = i - k * 81;
        float dy = om[(2 * k) * 81 + p];
        float dx = om[(2 * k + 1) * 81 + p];
        float m  = omm[i];
        int y = p / 9, xx = p - y * 9;
        float py = dy + (float)(y + k / 3 - 1);
        float px = dx + (float)(xx + (k % 3) - 1);
        float fy = floorf(py), fx = floorf(px);
        float ly = py - fy, lx = px - fx;
        int y0 = (int)fy, x0 = (int)fx;
        int y1 = y0 + 1, x1 = x0 + 1;
        bool vy0 = (y0 >= 0) & (y0 < 9), vy1 = (y1 >= 0) & (y1 < 9);
        bool vx0 = (x0 >= 0) & (x0 < 9), vx1 = (x1 >= 0) & (x1 < 9);
        float w00 = (vy0 && vx0) ? m * (1.f - ly) * (1.f - lx) : 0.f;
        float w01 = (vy0 && vx1) ? m * (1.f - ly) * lx : 0.f;
        float w10 = (vy1 && vx0) ? m * ly * (1.f - lx) : 0.f;
        float w11 = (vy1 && vx1) ? m * ly * lx : 0.f;
        int yc0 = min(max(y0, 0), 8), yc1 = min(max(y1, 0), 8);
        int xc0 = min(max(x0, 0), 8), xc1 = min(max(x1, 0), 8);
        unsigned q00 = yc0 * 9 + xc0, q01 = yc0 * 9 + xc1;
        unsigned q10 = yc1 * 9 + xc0, q11 = yc1 * 9 + xc1;
        bwt[i] = make_uint2((unsigned)f2bf(w00) | ((unsigned)f2bf(w01) << 16),
                            (unsigned)f2bf(w10) | ((unsigned)f2bf(w11) << 16));
        bix[i] = q00 | (q01 << 8) | (q10 << 16) | (q11 << 24);
    }
    __syncthreads();   // params visible; om/omm dead; vt region free for fills

    // ---- fill tap kk into vt: 648 half-slots (81 p x 8 16B-chunks)
    auto stage_tap = [&](int kk) {
        int kbase = kk * 81;
        const char* hc = (const char*)hsh;
#pragma unroll
        for (int j2 = 0; j2 < 3; ++j2) {
            int s = t + j2 * 256;
            if (j2 == 2 && s >= 648) break;
            int gg = s & 7, p = s >> 3;
            uint2 bw = bwt[kbase + p];
            unsigned ix = bix[kbase + p];
            float w00 = bfhi2f(bw.x << 16), w01 = bfhi2f(bw.x & 0xffff0000u);
            float w10 = bfhi2f(bw.y << 16), w11 = bfhi2f(bw.y & 0xffff0000u);
            unsigned q00 = ix & 255u, q01 = (ix >> 8) & 255u;
            unsigned q10 = (ix >> 16) & 255u, q11 = ix >> 24;
            int b00 = (int)((q00 << 8) | ((q00 & 15u) << 4));
            int b01 = (int)((q01 << 8) | ((q01 & 15u) << 4));
            int b10 = (int)((q10 << 8) | ((q10 & 15u) << 4));
            int b11 = (int)((q11 << 8) | ((q11 & 15u) << 4));
            unsigned res[4];
#pragma unroll
            for (int jj = 0; jj < 2; ++jj) {
                int off = gg * 32 + jj * 16;
                floatx4 a4 = *(const floatx4*)(hc + (b00 ^ off)) * w00;
                a4 += *(const floatx4*)(hc + (b01 ^ off)) * w01;
                a4 += *(const floatx4*)(hc + (b10 ^ off)) * w10;
                a4 += *(const floatx4*)(hc + (b11 ^ off)) * w11;
                unsigned pk0, pk1;
                asm("v_cvt_pk_bf16_f32 %0, %1, %2" : "=v"(pk0) : "v"(a4.x), "v"(a4.y));
                asm("v_cvt_pk_bf16_f32 %0, %1, %2" : "=v"(pk1) : "v"(a4.z), "v"(a4.w));
                res[2 * jj] = pk0; res[2 * jj + 1] = pk1;
            }
            int swzv = (p & 7) << 4;
            *(uint4*)(vtb + p * 128 + ((gg * 16) ^ swzv)) = make_uint4(res[0], res[1], res[2], res[3]);
        }
    };

    // ---- deform GEMM: wave = (m-pair mh) x (n-half nh2)
    int mh = wv >> 1, nh2 = wv & 1;
    int o0 = (2 * mh) * 16 + lr;
    int o1 = (2 * mh + 1) * 16 + lr;
    floatx4 accA[3], accB[3];
#pragma unroll
    for (int n = 0; n < 3; ++n) { accA[n] = (floatx4)0.f; accB[n] = (floatx4)0.f; }
    int rowb[3], swzn[3];
#pragma unroll
    for (int n = 0; n < 3; ++n) {
        int row = (nh2 * 3 + n) * 16 + lr; row = row > 80 ? 80 : row;
        rowb[n] = row * 128;
        swzn[n] = (row & 7) << 4;
    }

#pragma unroll
    for (int k = 0; k < 9; ++k) {
        stage_tap(k);
        __syncthreads();
        bfrag8 A00 = *(const bfrag8*)&wdt16[(k * 64 + o0) * 64 + lg * 8];
        bfrag8 A01 = *(const bfrag8*)&wdt16[(k * 64 + o0) * 64 + 32 + lg * 8];
        bfrag8 A10 = *(const bfrag8*)&wdt16[(k * 64 + o1) * 64 + lg * 8];
        bfrag8 A11 = *(const bfrag8*)&wdt16[(k * 64 + o1) * 64 + 32 + lg * 8];
        const char* vb = (const char*)vtb;
        __builtin_amdgcn_s_setprio(1);
#pragma unroll
        for (int n = 0; n < 3; ++n) {
            bfrag8 b0 = *(const bfrag8*)(vb + rowb[n] + ((lg * 16) ^ swzn[n]));
            bfrag8 b1 = *(const bfrag8*)(vb + rowb[n] + ((64 + lg * 16) ^ swzn[n]));
            accA[n] = __builtin_amdgcn_mfma_f32_16x16x32_bf16(A00, b0, accA[n], 0, 0, 0);
            accA[n] = __builtin_amdgcn_mfma_f32_16x16x32_bf16(A01, b1, accA[n], 0, 0, 0);
            accB[n] = __builtin_amdgcn_mfma_f32_16x16x32_bf16(A10, b0, accB[n], 0, 0, 0);
            accB[n] = __builtin_amdgcn_mfma_f32_16x16x32_bf16(A11, b1, accB[n], 0, 0, 0);
        }
        __builtin_amdgcn_s_setprio(0);
        if (k < 8) __syncthreads();
    }

    // ---- epilogue: bias, pre-BN output, BN2 stats (replicated buckets)
    float* outb = dout + OUT_H_BASE + (size_t)b * 5184;
    int bucket = (b & 31) << 6;
#pragma unroll
    for (int mm = 0; mm < 2; ++mm) {
#pragma unroll
        for (int j = 0; j < 4; ++j) {
            int oo = (2 * mh + mm) * 16 + lg * 4 + j;
            float bias = bd[oo];
            float ss = 0.f, qq = 0.f;
#pragma unroll
            for (int n = 0; n < 3; ++n) {
                int p = (nh2 * 3 + n) * 16 + lr;
                float v = (mm == 0 ? accA[n][j] : accB[n][j]) + bias;
                if (p < 81) { outb[oo * 81 + p] = v; ss += v; qq += v * v; }
            }
#pragma unroll
            for (int off = 1; off < 16; off <<= 1) {
                ss += __shfl_xor(ss, off);
                qq += __shfl_xor(qq, off);
            }
            if (lr == 0) { atomicAdd(&sum2[bucket + oo], ss); atomicAdd(&sq2[bucket + oo], qq); }
        }
    }
}

// ---------------- launch -------------------------------------------------------
extern "C" void kernel_launch(void* const* d_in, const int* in_sizes, int n_in,
                              void* d_out, int out_size, void* d_ws, size_t ws_size,
                              hipStream_t stream) {
    const float* x   = (const float*)d_in[0];
    const float* w1  = (const float*)d_in[1];
    const float* b1  = (const float*)d_in[2];
    const float* g1  = (const float*)d_in[3];
    const float* be1 = (const float*)d_in[4];
    const float* wo  = (const float*)d_in[5];
    const float* bo  = (const float*)d_in[6];
    const float* wm  = (const float*)d_in[7];
    const float* bm  = (const float*)d_in[8];
    const float* wd  = (const float*)d_in[9];
    const float* bd  = (const float*)d_in[10];
    const float* g2  = (const float*)d_in[11];
    const float* be2 = (const float*)d_in[12];
    float* dout = (float*)d_out;
    float* ws   = (float*)d_ws;

    float* h1    = ws + WS_H1;
    const unsigned short* wdt16 = (const unsigned short*)(ws + WS_WDT);
    const unsigned short* w1m   = (const unsigned short*)(ws + WS_W1M);
    const unsigned short* wcm   = (const unsigned short*)(ws + WS_WCM);
    float* stats = ws + WS_STATS;
    float* sum1 = stats,        *sq1 = stats + 2048;
    float* sum2 = stats + 4096, *sq2 = stats + 6144;

    // zero the replicated BN accumulators (ws is NOT re-poisoned between replays)
    hipMemsetAsync(stats, 0, 8192 * sizeof(float), stream);

    prep_weights<<<312, 256, 0, stream>>>(w1, wo, wm, wd, ws);
    conv1_mfma<<<BATCH, 256, 0, stream>>>(x, b1, w1m, h1, sum1, sq1);
    offdeform_mfma<<<BATCH, 256, 0, stream>>>(h1, wcm, wdt16, bo, bm, bd,
                                              sum1, sq1, g1, be1, dout, sum2, sq2);
    bn_apply2<<<2048, 256, 0, stream>>>(dout + OUT_H_BASE, sum2, sq2, g2, be2,
                                        BATCH * 5184, dout);
}

// Round 22
// 126.404 us; speedup vs baseline: 1.0192x; 1.0003x over previous
//
#include <hip/hip_runtime.h>
#include <hip/hip_bf16.h>

// Problem constants
#define BATCH   2048
#define HW      81          // 9x9
#define CIN     39
#define NPIX    (BATCH*HW)  // 165888

// ws layout (float offsets)
#define WS_H1     0              // 10,616,832 floats  (B,64,81)  PRE-BN h
#define WS_WDT    12109824       // 36,864 ushort bf16 [k][o][c]   (18,432 floats)
#define WS_W1M    12128256       // 24,576 ushort bf16 [12][64][32] (12,288 floats)
#define WS_WCM    12140544       // 18,432 ushort bf16 [18][32][32] (9,216 floats)
#define WS_STATS  12149760       // 8192 floats: sum1[2048],sq1[2048],sum2[2048],sq2[2048]

#define OUT_OFF_BASE 1
#define OUT_H_BASE   (1 + BATCH*18*81)   // 2985985

typedef __attribute__((ext_vector_type(8))) short bfrag8;
typedef __attribute__((ext_vector_type(4))) float floatx4;

__device__ __forceinline__ unsigned short f2bf(float f) {
    unsigned u = __builtin_bit_cast(unsigned, f);
    u += 0x7FFFu + ((u >> 16) & 1u);       // round-to-nearest-even
    return (unsigned short)(u >> 16);
}
__device__ __forceinline__ float bfhi2f(unsigned hi16) {   // hi16 already in bits 31..16
    return __builtin_bit_cast(float, hi16);
}

// ---------------- weight prep: fragment-ready bf16 layouts --------------------
__global__ void prep_weights(const float* __restrict__ w1, const float* __restrict__ wo,
                             const float* __restrict__ wm, const float* __restrict__ wd,
                             float* __restrict__ ws) {
    int idx = blockIdx.x * 256 + threadIdx.x;
    unsigned short* w1m = (unsigned short*)(ws + WS_W1M);
    unsigned short* wcm = (unsigned short*)(ws + WS_WCM);
    unsigned short* wdt16 = (unsigned short*)(ws + WS_WDT);
    if (idx < 24576) {
        int kk = idx & 31, o = (idx >> 5) & 63, s = idx >> 11;
        int tap, c; bool ok = true;
        if (s < 9)       { tap = s;             c = kk; }
        else if (s == 9) { tap = kk >> 3;       c = 32 + (kk & 7); }
        else if (s == 10){ tap = 4 + (kk >> 3); c = 32 + (kk & 7); }
        else             { tap = 8;             c = 32 + (kk & 7); ok = (kk < 8); }
        float v = (ok && c < CIN) ? w1[(o * CIN + c) * 9 + tap] : 0.f;
        w1m[idx] = f2bf(v);
        return;
    }
    int j = idx - 24576;
    if (j >= 0 && j < 18432) {
        int kk = j & 31, oc = (j >> 5) & 31, s = j >> 10;
        int tap = s >> 1, c = (s & 1) * 32 + kk;
        float v = 0.f;
        if (oc < 18)      v = wo[(oc * 64 + c) * 9 + tap];
        else if (oc < 27) v = wm[((oc - 18) * 64 + c) * 9 + tap];
        wcm[j] = f2bf(v);
        return;
    }
    int m = idx - 24576 - 18432;
    if (m >= 0 && m < 36864) {
        int c = m & 63, o = (m >> 6) & 63, k = m >> 12;
        wdt16[m] = f2bf(wd[(o * 64 + c) * 9 + k]);
    }
}

// ---------------- conv1 (39->64) MFMA + ReLU + BN1 stats ----------------------
__global__ __launch_bounds__(256, 4) void conv1_mfma(
        const float* __restrict__ xg, const float* __restrict__ b1,
        const unsigned short* __restrict__ w1m, float* __restrict__ h1,
        float* __restrict__ sum1, float* __restrict__ sq1) {
    __shared__ short xs[128 * 64];   // [r(121)][c(64)] bf16, byte ^= (r&7)<<4
    int b = blockIdx.x, t = threadIdx.x;
    for (int i = t; i < 4096; i += 256) ((unsigned*)xs)[i] = 0u;
    __syncthreads();
    const float* xb = xg + (size_t)b * (HW * CIN);
    const float4* xb4 = (const float4*)xb;
    for (int i4 = t; i4 < 789; i4 += 256) {
        float4 v = xb4[i4];
        float vv[4] = { v.x, v.y, v.z, v.w };
        int base = 4 * i4;
#pragma unroll
        for (int k = 0; k < 4; ++k) {
            int idx = base + k;
            int p = idx / 39, c = idx - 39 * p;
            int y = p / 9, xx = p - 9 * y;
            int r = (y + 1) * 11 + xx + 1;
            int byte = r * 128 + ((c * 2) ^ ((r & 7) << 4));
            xs[byte >> 1] = (short)f2bf(vv[k]);
        }
    }
    if (t < 3) {
        int idx = 3156 + t;
        int p = idx / 39, c = idx - 39 * p;
        int y = p / 9, xx = p - 9 * y;
        int r = (y + 1) * 11 + xx + 1;
        int byte = r * 128 + ((c * 2) ^ ((r & 7) << 4));
        xs[byte >> 1] = (short)f2bf(xb[idx]);
    }
    __syncthreads();
    int lane = t & 63, wv = t >> 6, lg = lane >> 4, lr = lane & 15;
    int o = wv * 16 + lr;
    floatx4 acc[6];
#pragma unroll
    for (int n = 0; n < 6; ++n) acc[n] = (floatx4)0.f;
    int rbn[6];
#pragma unroll
    for (int n = 0; n < 6; ++n) {
        int p = n * 16 + lr; p = p > 80 ? 80 : p;
        int y = p / 9, xx = p - 9 * y;
        rbn[n] = (y + 1) * 11 + xx + 1;
    }
#pragma unroll
    for (int s = 0; s < 12; ++s) {
        bfrag8 a = *(const bfrag8*)&w1m[(s * 64 + o) * 32 + lg * 8];
        int roff, cb;
        if (s < 9)       { roff = (s / 3 - 1) * 11 + (s % 3) - 1; cb = lg * 16; }
        else if (s == 9) { roff = (lg / 3 - 1) * 11 + (lg % 3) - 1; cb = 64; }
        else if (s == 10){ int tp = lg + 4; roff = (tp / 3 - 1) * 11 + (tp % 3) - 1; cb = 64; }
        else             { roff = 12; cb = 64; }
#pragma unroll
        for (int n = 0; n < 6; ++n) {
            int r = rbn[n] + roff;
            int byte = r * 128 + (cb ^ ((r & 7) << 4));
            bfrag8 bf = *(const bfrag8*)((const char*)xs + byte);
            acc[n] = __builtin_amdgcn_mfma_f32_16x16x32_bf16(a, bf, acc[n], 0, 0, 0);
        }
    }
    float* h1b = h1 + (size_t)b * 5184;
    int bucket = (b & 31) << 6;
#pragma unroll
    for (int j = 0; j < 4; ++j) {
        int oo = wv * 16 + lg * 4 + j;
        float bias = b1[oo];
        float ss = 0.f, qq = 0.f;
#pragma unroll
        for (int n = 0; n < 6; ++n) {
            int p = n * 16 + lr;
            float v = fmaxf(acc[n][j] + bias, 0.f);
            if (p < 81) { h1b[oo * 81 + p] = v; ss += v; qq += v * v; }
        }
#pragma unroll
        for (int off = 1; off < 16; off <<= 1) { ss += __shfl_xor(ss, off); qq += __shfl_xor(qq, off); }
        if (lr == 0) { atomicAdd(&sum1[bucket + oo], ss); atomicAdd(&sq1[bucket + oo], qq); }
    }
}

// ---------------- BN2 finalize + apply (fused; aligned float4 body) -----------
__global__ __launch_bounds__(256) void bn_apply2(
        float* __restrict__ data, const float* __restrict__ sums,
        const float* __restrict__ sqs, const float* __restrict__ gamma,
        const float* __restrict__ beta, int n, float* __restrict__ dout) {
    __shared__ float sc[64], sh[64];
    int t = threadIdx.x;
    if (t < 64) {
        float s = 0.f, q = 0.f;
#pragma unroll
        for (int r = 0; r < 32; ++r) { s += sums[(r << 6) + t]; q += sqs[(r << 6) + t]; }
        float m = s / (float)NPIX;
        float v = q / (float)NPIX - m * m;
        float scv = gamma[t] * (1.f / sqrtf(v + 1e-5f));
        sc[t] = scv; sh[t] = beta[t] - m * scv;
    }
    __syncthreads();
    if (blockIdx.x == 0) {
        if (t == 0) dout[0] = 0.5f;
        if (t < 3) data[t] = data[t] * sc[0] + sh[0];   // e<81 -> c=0
        if (t == 3) {
            int e = n - 1;
            int c = (e / 81) & 63;
            data[e] = data[e] * sc[c] + sh[c];
        }
    }
    float4* d4 = (float4*)(data + 3);
    int n4 = (n - 4) >> 2;    // covers elements 3 .. n-2
    for (int i = blockIdx.x * 256 + t; i < n4; i += gridDim.x * 256) {
        float4 v = d4[i];
        unsigned e = 3u + 4u * (unsigned)i;
        int c0 = (int)((e) / 81u) & 63;
        int c1 = (int)((e + 1) / 81u) & 63;
        int c2 = (int)((e + 2) / 81u) & 63;
        int c3 = (int)((e + 3) / 81u) & 63;
        v.x = v.x * sc[c0] + sh[c0];
        v.y = v.y * sc[c1] + sh[c1];
        v.z = v.z * sc[c2] + sh[c2];
        v.w = v.w * sc[c3] + sh[c3];
        d4[i] = v;
    }
}

// ---------------- FUSED offset/mask conv + deformable conv (MFMA) --------------
// r20 structure exactly + T5: s_setprio(1) around the deform MFMA cluster.
// Resident blocks are phase-staggered (fill vs MFMA), so priority arbitration
// between blocks' waves on the same SIMD can favor the matrix pipe.
//   hsh [0,20736)      f32 [q][256B], byte q*256 + ((c*4)^((q&15)<<4))
//   bwt [20736,26568)  uint2[729]  (first 512B = sc1/sh1 during P0)
//   bix [26568,29484)  uint[729]
//   xs/om/vt [29488,39984) xs bf16 [r(82)][128B] (P0/P1, row 81 zeros);
//                       om f32[1458]+omm f32[729] (P1 epi..P2); vt (fills)
__global__ __launch_bounds__(256, 4) void offdeform_mfma(
        const float* __restrict__ h1, const unsigned short* __restrict__ wcm,
        const unsigned short* __restrict__ wdt16,
        const float* __restrict__ bo, const float* __restrict__ bm,
        const float* __restrict__ bd,
        const float* __restrict__ sum1, const float* __restrict__ sq1,
        const float* __restrict__ g1, const float* __restrict__ be1,
        float* __restrict__ dout, float* __restrict__ sum2, float* __restrict__ sq2) {
    __shared__ __align__(16) char L[39984];
    float*    hsh = (float*)L;
    uint2*    bwt = (uint2*)(L + 20736);
    unsigned* bix = (unsigned*)(L + 26568);
    char*     vtb = L + 29488;               // xs (P0/P1) -> om/omm (P1..P2) -> vt
    float*    om  = (float*)(L + 29488);     // 1458 f32
    float*    omm = (float*)(L + 29488) + 1458; // 729 f32
    float*    sc1 = (float*)(L + 20736);     // alias bwt[0..64)   (P0 only)
    float*    sh1 = (float*)(L + 20992);     // alias bwt[64..128) (P0 only)

    int b = blockIdx.x, t = threadIdx.x;
    int lane = t & 63, wv = t >> 6, lg = lane >> 4, lr = lane & 15;

    // ---- BN1 finalize folded in (per block, cheap)
    if (t < 64) {
        float s = 0.f, q = 0.f;
#pragma unroll
        for (int r = 0; r < 32; ++r) { s += sum1[(r << 6) + t]; q += sq1[(r << 6) + t]; }
        float m = s / (float)NPIX;
        float v = q / (float)NPIX - m * m;
        float scv = g1[t] * (1.f / sqrtf(v + 1e-5f));
        sc1[t] = scv; sh1[t] = be1[t] - m * scv;
    }
    __syncthreads();

    // ---- P0: stage h as f32 hsh (swizzled) + bf16 xs (vt layout), BN1 folded
    const float* hb = h1 + (size_t)b * 5184;
    for (int i = t; i < 2592; i += 256) {
        int c2 = i / 81, q = i - c2 * 81;
        int c = 2 * c2;
        float va = hb[c * 81 + q]      * sc1[c]     + sh1[c];
        float vb = hb[c * 81 + 81 + q] * sc1[c + 1] + sh1[c + 1];
        *(float2*)((char*)hsh + q * 256 + ((c * 4) ^ ((q & 15) << 4))) = make_float2(va, vb);
        unsigned pk;
        asm("v_cvt_pk_bf16_f32 %0, %1, %2" : "=v"(pk) : "v"(va), "v"(vb));
        *(unsigned*)(vtb + q * 128 + ((c * 2) ^ ((q & 7) << 4))) = pk;
    }
    if (t < 32) *(unsigned*)(vtb + 81 * 128 + t * 4) = 0u;   // zero row 81
    __syncthreads();

    // ---- P1: offset/mask GEMM; OOB fragments -> zero row (no select)
    int mt = wv >> 1, nh = (wv & 1) * 3;
    int ocr = mt * 16 + lr;
    floatx4 oacc[3];
#pragma unroll
    for (int n = 0; n < 3; ++n) oacc[n] = (floatx4)0.f;
    int yn[3], xn[3];
#pragma unroll
    for (int ni = 0; ni < 3; ++ni) {
        int p = (nh + ni) * 16 + lr; p = p > 80 ? 80 : p;
        yn[ni] = p / 9; xn[ni] = p - 9 * yn[ni];
    }
#pragma unroll
    for (int s = 0; s < 18; ++s) {
        const int tap = s >> 1, dyk = tap / 3 - 1, dxk = tap % 3 - 1;
        const int cb1 = (s & 1) * 64 + lg * 16;
        bfrag8 af = *(const bfrag8*)&wcm[(s * 32 + ocr) * 32 + lg * 8];
#pragma unroll
        for (int ni = 0; ni < 3; ++ni) {
            int yy = yn[ni] + dyk, xx2 = xn[ni] + dxk;
            bool val = ((unsigned)yy < 9u) & ((unsigned)xx2 < 9u);
            int q2 = val ? yy * 9 + xx2 : 81;
            bfrag8 bf = *(const bfrag8*)(vtb + q2 * 128 + (cb1 ^ ((q2 & 7) << 4)));
            oacc[ni] = __builtin_amdgcn_mfma_f32_16x16x32_bf16(af, bf, oacc[ni], 0, 0, 0);
        }
    }
    __syncthreads();   // ALL waves done reading xs before om/omm overwrite it

    // P1 epilogue: offsets -> dout (output) + om (LDS); mask -> omm (LDS)
#pragma unroll
    for (int j = 0; j < 4; ++j) {
        int oc = mt * 16 + lg * 4 + j;
        if (oc < 18) {
            float bias = bo[oc];
            float* ob = dout + OUT_OFF_BASE + (size_t)b * 1458 + oc * 81;
#pragma unroll
            for (int ni = 0; ni < 3; ++ni) {
                int p = (nh + ni) * 16 + lr;
                if (p < 81) { float v = oacc[ni][j] + bias; ob[p] = v; om[oc * 81 + p] = v; }
            }
        } else if (oc < 27) {
            float bias = bm[oc - 18];
#pragma unroll
            for (int ni = 0; ni < 3; ++ni) {
                int p = (nh + ni) * 16 + lr;
                if (p < 81) { float v = oacc[ni][j] + bias; omm[(oc - 18) * 81 + p] = 1.f / (1.f + expf(-v)); }
            }
        }
    }
    __syncthreads();   // om/omm visible to all waves

    // ---- P2: bilinear params per (tap,pixel) from LDS om/omm -> bwt/bix
    for (int i = t; i < 729; i += 256) {
        int k = i / 81, p = i - k * 81;
        float dy = om[(2 * k) * 81 + p];
        float dx = om[(2 * k + 1) * 81 + p];
        float m  = omm[i];
        int y = p / 9, xx = p - y * 9;
        float py = dy + (float)(y + k / 3 - 1);
        float px = dx + (float)(xx + (k % 3) - 1);
        float fy = floorf(py), fx = floorf(px);
        float ly = py - fy, lx = px - fx;
        int y0 = (int)fy, x0 = (int)fx;
        int y1 = y0 + 1, x1 = x0 + 1;
        bool vy0 = (y0 >= 0) & (y0 < 9), vy1 = (y1 >= 0) & (y1 < 9);
        bool vx0 = (x0 >= 0) & (x0 < 9), vx1 = (x1 >= 0) & (x1 < 9);
        float w00 = (vy0 && vx0) ? m * (1.f - ly) * (1.f - lx) : 0.f;
        float w01 = (vy0 && vx1) ? m * (1.f - ly) * lx : 0.f;
        float w10 = (vy1 && vx0) ? m * ly * (1.f - lx) : 0.f;
        float w11 = (vy1 && vx1) ? m * ly * lx : 0.f;
        int yc0 = min(max(y0, 0), 8), yc1 = min(max(y1, 0), 8);
        int xc0 = min(max(x0, 0), 8), xc1 = min(max(x1, 0), 8);
        unsigned q00 = yc0 * 9 + xc0, q01 = yc0 * 9 + xc1;
        unsigned q10 = yc1 * 9 + xc0, q11 = yc1 * 9 + xc1;
        bwt[i] = make_uint2((unsigned)f2bf(w00) | ((unsigned)f2bf(w01) << 16),
                            (unsigned)f2bf(w10) | ((unsigned)f2bf(w11) << 16));
        bix[i] = q00 | (q01 << 8) | (q10 << 16) | (q11 << 24);
    }
    __syncthreads();   // params visible; om/omm dead; vt region free for fills

    // ---- fill tap kk into vt: 648 half-slots (81 p x 8 16B-chunks)
    auto stage_tap = [&](int kk) {
        int kbase = kk * 81;
        const char* hc = (const char*)hsh;
#pragma unroll
        for (int j2 = 0; j2 < 3; ++j2) {
            int s = t + j2 * 256;
            if (j2 == 2 && s >= 648) break;
            int gg = s & 7, p = s >> 3;
            uint2 bw = bwt[kbase + p];
            unsigned ix = bix[kbase + p];
            float w00 = bfhi2f(bw.x << 16), w01 = bfhi2f(bw.x & 0xffff0000u);
            float w10 = bfhi2f(bw.y << 16), w11 = bfhi2f(bw.y & 0xffff0000u);
            unsigned q00 = ix & 255u, q01 = (ix >> 8) & 255u;
            unsigned q10 = (ix >> 16) & 255u, q11 = ix >> 24;
            int b00 = (int)((q00 << 8) | ((q00 & 15u) << 4));
            int b01 = (int)((q01 << 8) | ((q01 & 15u) << 4));
            int b10 = (int)((q10 << 8) | ((q10 & 15u) << 4));
            int b11 = (int)((q11 << 8) | ((q11 & 15u) << 4));
            unsigned res[4];
#pragma unroll
            for (int jj = 0; jj < 2; ++jj) {
                int off = gg * 32 + jj * 16;
                floatx4 a4 = *(const floatx4*)(hc + (b00 ^ off)) * w00;
                a4 += *(const floatx4*)(hc + (b01 ^ off)) * w01;
                a4 += *(const floatx4*)(hc + (b10 ^ off)) * w10;
                a4 += *(const floatx4*)(hc + (b11 ^ off)) * w11;
                unsigned pk0, pk1;
                asm("v_cvt_pk_bf16_f32 %0, %1, %2" : "=v"(pk0) : "v"(a4.x), "v"(a4.y));
                asm("v_cvt_pk_bf16_f32 %0, %1, %2" : "=v"(pk1) : "v"(a4.z), "v"(a4.w));
                res[2 * jj] = pk0; res[2 * jj + 1] = pk1;
            }
            int swzv = (p & 7) << 4;
            *(uint4*)(vtb + p * 128 + ((gg * 16) ^ swzv)) = make_uint4(res[0], res[1], res[2], res[3]);
        }
    };

    // ---- deform GEMM: wave = (m-pair mh) x (n-half nh2)
    int mh = wv >> 1, nh2 = wv & 1;
    int o0 = (2 * mh) * 16 + lr;
    int o1 = (2 * mh + 1) * 16 + lr;
    floatx4 accA[3], accB[3];
#pragma unroll
    for (int n = 0; n < 3; ++n) { accA[n] = (floatx4)0.f; accB[n] = (floatx4)0.f; }
    int rowb[3], swzn[3];
#pragma unroll
    for (int n = 0; n < 3; ++n) {
        int row = (nh2 * 3 + n) * 16 + lr; row = row > 80 ? 80 : row;
        rowb[n] = row * 128;
        swzn[n] = (row & 7) << 4;
    }

#pragma unroll
    for (int k = 0; k < 9; ++k) {
        stage_tap(k);
        __syncthreads();
        bfrag8 A00 = *(const bfrag8*)&wdt16[(k * 64 + o0) * 64 + lg * 8];
        bfrag8 A01 = *(const bfrag8*)&wdt16[(k * 64 + o0) * 64 + 32 + lg * 8];
        bfrag8 A10 = *(const bfrag8*)&wdt16[(k * 64 + o1) * 64 + lg * 8];
        bfrag8 A11 = *(const bfrag8*)&wdt16[(k * 64 + o1) * 64 + 32 + lg * 8];
        const char* vb = (const char*)vtb;
        __builtin_amdgcn_s_setprio(1);
#pragma unroll
        for (int n = 0; n < 3; ++n) {
            bfrag8 b0 = *(const bfrag8*)(vb + rowb[n] + ((lg * 16) ^ swzn[n]));
            bfrag8 b1 = *(const bfrag8*)(vb + rowb[n] + ((64 + lg * 16) ^ swzn[n]));
            accA[n] = __builtin_amdgcn_mfma_f32_16x16x32_bf16(A00, b0, accA[n], 0, 0, 0);
            accA[n] = __builtin_amdgcn_mfma_f32_16x16x32_bf16(A01, b1, accA[n], 0, 0, 0);
            accB[n] = __builtin_amdgcn_mfma_f32_16x16x32_bf16(A10, b0, accB[n], 0, 0, 0);
            accB[n] = __builtin_amdgcn_mfma_f32_16x16x32_bf16(A11, b1, accB[n], 0, 0, 0);
        }
        __builtin_amdgcn_s_setprio(0);
        if (k < 8) __syncthreads();
    }

    // ---- epilogue: bias, pre-BN output, BN2 stats (replicated buckets)
    float* outb = dout + OUT_H_BASE + (size_t)b * 5184;
    int bucket = (b & 31) << 6;
#pragma unroll
    for (int mm = 0; mm < 2; ++mm) {
#pragma unroll
        for (int j = 0; j < 4; ++j) {
            int oo = (2 * mh + mm) * 16 + lg * 4 + j;
            float bias = bd[oo];
            float ss = 0.f, qq = 0.f;
#pragma unroll
            for (int n = 0; n < 3; ++n) {
                int p = (nh2 * 3 + n) * 16 + lr;
                float v = (mm == 0 ? accA[n][j] : accB[n][j]) + bias;
                if (p < 81) { outb[oo * 81 + p] = v; ss += v; qq += v * v; }
            }
#pragma unroll
            for (int off = 1; off < 16; off <<= 1) {
                ss += __shfl_xor(ss, off);
                qq += __shfl_xor(qq, off);
            }
            if (lr == 0) { atomicAdd(&sum2[bucket + oo], ss); atomicAdd(&sq2[bucket + oo], qq); }
        }
    }
}

// ---------------- launch -------------------------------------------------------
extern "C" void kernel_launch(void* const* d_in, const int* in_sizes, int n_in,
                              void* d_out, int out_size, void* d_ws, size_t ws_size,
                              hipStream_t stream) {
    const float* x   = (const float*)d_in[0];
    const float* w1  = (const float*)d_in[1];
    const float* b1  = (const float*)d_in[2];
    const float* g1  = (const float*)d_in[3];
    const float* be1 = (const float*)d_in[4];
    const float* wo  = (const float*)d_in[5];
    const float* bo  = (const float*)d_in[6];
    const float* wm  = (const float*)d_in[7];
    const float* bm  = (const float*)d_in[8];
    const float* wd  = (const float*)d_in[9];
    const float* bd  = (const float*)d_in[10];
    const float* g2  = (const float*)d_in[11];
    const float* be2 = (const float*)d_in[12];
    float* dout = (float*)d_out;
    float* ws   = (float*)d_ws;

    float* h1    = ws + WS_H1;
    const unsigned short* wdt16 = (const unsigned short*)(ws + WS_WDT);
    const unsigned short* w1m   = (const unsigned short*)(ws + WS_W1M);
    const unsigned short* wcm   = (const unsigned short*)(ws + WS_WCM);
    float* stats = ws + WS_STATS;
    float* sum1 = stats,        *sq1 = stats + 2048;
    float* sum2 = stats + 4096, *sq2 = stats + 6144;

    // zero the replicated BN accumulators (ws is NOT re-poisoned between replays)
    hipMemsetAsync(stats, 0, 8192 * sizeof(float), stream);

    prep_weights<<<312, 256, 0, stream>>>(w1, wo, wm, wd, ws);
    conv1_mfma<<<BATCH, 256, 0, stream>>>(x, b1, w1m, h1, sum1, sq1);
    offdeform_mfma<<<BATCH, 256, 0, stream>>>(h1, wcm, wdt16, bo, bm, bd,
                                              sum1, sq1, g1, be1, dout, sum2, sq2);
    bn_apply2<<<2048, 256, 0, stream>>>(dout + OUT_H_BASE, sum2, sq2, g2, be2,
                                        BATCH * 5184, dout);
}